// Round 15
// baseline (622.687 us; speedup 1.0000x reference)
//
#include <hip/hip_runtime.h>
#include <stdint.h>

static constexpr int NB    = 4;
static constexpr int NP    = 8192;
static constexpr int KK    = 20;
static constexpr int SPLIT = 4;
static constexpr int SEG   = NP / SPLIT;   // 2048 candidates per segment/wave
static constexpr int QPB   = 64;           // queries per block (one per lane)
static constexpr int TPB   = QPB * SPLIT;  // 256 threads
static constexpr int CAP   = 36;           // log capacity (entries) per thread
static constexpr int CAPP  = 37;           // padded stride (last slot = sentinel)
static constexpr int XOFF  = NB * NP * 16; // offset of idx output in d_out
static constexpr float MARGIN = 5e-4f;     // >> worst-case |screen - d_ref|

// ---- contraction-proof scalar fp32 ops (inline asm; fp-contract pragma is
// proven ineffective under hipcc: R1==R3==R4 bitwise) ----
__device__ __forceinline__ float vadd(float a, float b) {
  float r; asm("v_add_f32 %0, %1, %2" : "=v"(r) : "v"(a), "v"(b)); return r;
}
__device__ __forceinline__ float vsub(float a, float b) {
  float r; asm("v_sub_f32 %0, %1, %2" : "=v"(r) : "v"(a), "v"(b)); return r;
}
__device__ __forceinline__ float vmul(float a, float b) {
  float r; asm("v_mul_f32 %0, %1, %2" : "=v"(r) : "v"(a), "v"(b)); return r;
}
// acc += a*b as a guaranteed single FMA (BLAS micro-kernel semantics).
__device__ __forceinline__ float vfmac(float acc, float a, float b) {
  asm("v_fmac_f32 %0, %1, %2" : "+v"(acc) : "v"(a), "v"(b)); return acc;
}

// ---- fast fp32 screen dot (FMA tree; accuracy covered by MARGIN) ----
__device__ __forceinline__ float dot16v(const float4 a0, const float4 a1,
                                        const float4 a2, const float4 a3,
                                        const float4 b0, const float4 b1,
                                        const float4 b2, const float4 b3) {
  float g0 = fmaf(a3.x, b3.x, fmaf(a2.x, b2.x, fmaf(a1.x, b1.x, a0.x * b0.x)));
  float g1 = fmaf(a3.y, b3.y, fmaf(a2.y, b2.y, fmaf(a1.y, b1.y, a0.y * b0.y)));
  float g2 = fmaf(a3.z, b3.z, fmaf(a2.z, b2.z, fmaf(a1.z, b1.z, a0.z * b0.z)));
  float g3 = fmaf(a3.w, b3.w, fmaf(a2.w, b2.w, fmaf(a1.w, b1.w, a0.w * b0.w)));
  return (g0 + g1) + (g2 + g3);
}

// ---- BLAS sgemm exact dot (einsum->tensordot->sgemm path): single
// accumulator, ascending k, one FMA per step; acc starts at fl(a0*b0).
// Asm-hardened v_fmac chain — cannot be reassociated. ----
__device__ __forceinline__ float dot16_ref(const float4 a0, const float4 a1,
                                           const float4 a2, const float4 a3,
                                           const float4 b0, const float4 b1,
                                           const float4 b2, const float4 b3) {
  float acc = vmul(a0.x, b0.x);
  acc = vfmac(acc, a0.y, b0.y);
  acc = vfmac(acc, a0.z, b0.z);
  acc = vfmac(acc, a0.w, b0.w);
  acc = vfmac(acc, a1.x, b1.x);
  acc = vfmac(acc, a1.y, b1.y);
  acc = vfmac(acc, a1.z, b1.z);
  acc = vfmac(acc, a1.w, b1.w);
  acc = vfmac(acc, a2.x, b2.x);
  acc = vfmac(acc, a2.y, b2.y);
  acc = vfmac(acc, a2.z, b2.z);
  acc = vfmac(acc, a2.w, b2.w);
  acc = vfmac(acc, a3.x, b3.x);
  acc = vfmac(acc, a3.y, b3.y);
  acc = vfmac(acc, a3.z, b3.z);
  acc = vfmac(acc, a3.w, b3.w);
  return acc;
}

// ---- numpy FLOAT_pairwise_sum exact xx — npyv SSE path (vstep=4), which is
// BASELINE-compiled in numpy (not runtime-dispatched), n=16 unit stride:
//   t_k = fl(x_k*x_k)  (separate rounding, no FMA);
//   r01 = t[0:4] + t[8:12];  r23 = t[4:8] + t[12:16];  s = r01 + r23
//     -> lane j: s_j = (t_j + t_{8+j}) + (t_{4+j} + t_{12+j})
//   hsum (SSE3 hadd): (s0+s1) + (s2+s3).  Asm-hardened. ----
__device__ __forceinline__ float xx16_ref(const float4 a0, const float4 a1,
                                          const float4 a2, const float4 a3) {
  // t0..t3 = a0.*, t4..t7 = a1.*, t8..t11 = a2.*, t12..t15 = a3.*
  float s0 = vadd(vadd(vmul(a0.x, a0.x), vmul(a2.x, a2.x)),
                  vadd(vmul(a1.x, a1.x), vmul(a3.x, a3.x)));
  float s1 = vadd(vadd(vmul(a0.y, a0.y), vmul(a2.y, a2.y)),
                  vadd(vmul(a1.y, a1.y), vmul(a3.y, a3.y)));
  float s2 = vadd(vadd(vmul(a0.z, a0.z), vmul(a2.z, a2.z)),
                  vadd(vmul(a1.z, a1.z), vmul(a3.z, a3.z)));
  float s3 = vadd(vadd(vmul(a0.w, a0.w), vmul(a2.w, a2.w)),
                  vadd(vmul(a1.w, a1.w), vmul(a3.w, a3.w)));
  return vadd(vadd(s0, s1), vadd(s2, s3));
}

// ---- reference-exact combine: (xxq - fl(2*dot)) + xxc, separate roundings,
// asm-hardened against re-fusion ----
__device__ __forceinline__ float dref_combine(float xxq, float dot, float xxc) {
  float t = vmul(2.0f, dot);
  float d1 = vsub(xxq, t);
  return vadd(d1, xxc);
}

__device__ __forceinline__ unsigned umin_(unsigned a, unsigned b) { return a < b ? a : b; }
__device__ __forceinline__ unsigned umax_(unsigned a, unsigned b) { return a < b ? b : a; }

// Monotone total-order u32 key for f32 (handles tiny negative diag dust).
__device__ __forceinline__ unsigned floatToKey(float f) {
  unsigned db = __float_as_uint(f);
  return db ^ ((unsigned)((int)db >> 31) | 0x80000000u);
}
__device__ __forceinline__ float keyToFloat(unsigned k) {
  unsigned bits = (k & 0x80000000u) ? (k ^ 0x80000000u) : ~k;
  return __uint_as_float(bits);
}

// Screen-space compaction: keep entries <= (20th smallest screen d) + MARGIN.
__device__ __forceinline__ void compactlog(unsigned long long* lg, int& wc, float& thrF) {
  unsigned ch[20];
#pragma unroll
  for (int i = 0; i < 20; ++i) ch[i] = 0xFFFFFFFFu;
  for (int i = 0; i < wc; ++i) {
    unsigned hi = (unsigned)(lg[i] >> 32);
    if (hi < ch[0]) {
#pragma unroll
      for (int j = 0; j < 19; ++j) ch[j] = umin_(ch[j], umax_(ch[j + 1], hi));
      ch[19] = umin_(ch[19], hi);
    }
  }
  const float nt = keyToFloat(ch[0]) + MARGIN;
  const unsigned kThr = floatToKey(nt);
  int w2 = 0;
  for (int i = 0; i < wc; ++i) {
    unsigned long long e = lg[i];
    if ((unsigned)(e >> 32) <= kThr) lg[w2++] = e;
  }
  wc = w2;
  thrF = nt;
}

// Prep: bit-exact copy of x into output slot 0, and xxf[p] (reference order).
__global__ __launch_bounds__(256) void knn_prep_kernel(const float* __restrict__ x,
                                                       float* __restrict__ outx,
                                                       float* __restrict__ xxf) {
  int p = blockIdx.x * 256 + threadIdx.x;  // exact grid: 32768 points
  const float4* s = reinterpret_cast<const float4*>(x) + (size_t)p * 4;
  float4* d = reinterpret_cast<float4*>(outx) + (size_t)p * 4;
  float4 v0 = s[0], v1 = s[1], v2 = s[2], v3 = s[3];
  d[0] = v0; d[1] = v1; d[2] = v2; d[3] = v3;
  xxf[p] = xx16_ref(v0, v1, v2, v3);
}

__global__ __launch_bounds__(256) void knn_main_kernel(const float* __restrict__ x,
                                                       const float* __restrict__ xxf,
                                                       float* __restrict__ oidx) {
  __shared__ unsigned long long logbuf[TPB * CAPP];  // 75776 B -> 2 blocks/CU
  const int tid  = threadIdx.x;
  const int lane = tid & 63;    // query within block
  const int seg  = tid >> 6;    // segment == wave id (wave-uniform)
  const int qg   = blockIdx.x * QPB + lane;  // global query 0..32767
  const int b    = qg >> 13;                 // batch (uniform per block)

  const float4* qp = reinterpret_cast<const float4*>(x) + (size_t)qg * 4;
  const float4 q0 = qp[0], q1 = qp[1], q2 = qp[2], q3 = qp[3];
  const float xxq = xxf[qg];

  // Wave-uniform candidate base -> broadcast loads.
  const int sb = __builtin_amdgcn_readfirstlane(b * NP + seg * SEG);
  const float4* cb  = reinterpret_cast<const float4*>(x) + (size_t)sb * 4;
  const float*  xxb = xxf + sb;

  unsigned long long* mylog = logbuf + tid * CAPP;
  float thrF = __builtin_huge_valf();
  int wc = 0;

  // --- fp32 FMA screen with conservative margin, geometric windows.
  int t0 = 0;
#pragma unroll 1
  while (t0 < SEG) {
    int t1 = t0 + (t0 * 35) / 100;
    if (t1 < 32) t1 = 32;
    if (t1 > SEG) t1 = SEG;
#pragma unroll 2
    for (int t = t0; t < t1; ++t) {
      const float4 c0 = cb[(size_t)t * 4 + 0];
      const float4 c1 = cb[(size_t)t * 4 + 1];
      const float4 c2 = cb[(size_t)t * 4 + 2];
      const float4 c3 = cb[(size_t)t * 4 + 3];
      const float xxc = xxb[t];
      const float dot = dot16v(q0, q1, q2, q3, c0, c1, c2, c3);
      const float d   = fmaf(-2.0f, dot, xxq) + xxc;
      if (d <= thrF) {
        if (wc == CAP) compactlog(mylog, wc, thrF);   // rare emergency
        if (wc < CAP) {
          const unsigned fk = floatToKey(d);
          mylog[wc++] = ((unsigned long long)fk << 32) | (unsigned)(seg * SEG + t);
        }
      }
    }
    t0 = t1;
    if (wc > 20) compactlog(mylog, wc, thrF);
  }

  // --- reference-bit-exact fp32 re-keying of survivors (~21 per thread).
  const int brow = b * NP;
  for (int i = 0; i < wc; ++i) {
    const unsigned e = (unsigned)mylog[i] & 0x1FFFu;  // candidate idx 0..8191
    const float4* cp = reinterpret_cast<const float4*>(x) + (size_t)(brow + e) * 4;
    const float4 c0 = cp[0], c1 = cp[1], c2 = cp[2], c3 = cp[3];
    const float dot = dot16_ref(q0, q1, q2, q3, c0, c1, c2, c3);
    const float dref = dref_combine(xxq, dot, xxf[brow + e]);
    // 45-bit key: (monotone d key << 13) | idx -> ascending (d, idx),
    // matching stable lower-index tie-break.
    mylog[i] = ((unsigned long long)floatToKey(dref) << 13) | (unsigned long long)e;
  }

  // Per-thread insertion sort ascending by (d, idx).
  for (int i = 1; i < wc; ++i) {
    unsigned long long key = mylog[i];
    int j = i - 1;
    while (j >= 0 && mylog[j] > key) {
      mylog[j + 1] = mylog[j];
      --j;
    }
    mylog[j + 1] = key;
  }
  mylog[wc] = ~0ULL;  // sentinel (slot CAP=36 exists; wc<=36)
  __syncthreads();

  // 4-way merge of the per-segment sorted lists; one thread per query.
  if (tid < QPB) {
    const int mq = blockIdx.x * QPB + tid;
    unsigned long long h0 = logbuf[(0 * QPB + tid) * CAPP + 0];
    unsigned long long h1 = logbuf[(1 * QPB + tid) * CAPP + 0];
    unsigned long long h2 = logbuf[(2 * QPB + tid) * CAPP + 0];
    unsigned long long h3 = logbuf[(3 * QPB + tid) * CAPP + 0];
    int p0 = 1, p1 = 1, p2 = 1, p3 = 1;
    float* dst = oidx + (size_t)mq * KK;
#pragma unroll 1
    for (int r = 0; r < KK; ++r) {
      const unsigned long long m01 = (h0 < h1) ? h0 : h1;
      const unsigned long long m23 = (h2 < h3) ? h2 : h3;
      const unsigned long long m = (m01 < m23) ? m01 : m23;
      dst[r] = (float)(unsigned)(m & 0x1FFFull);  // low 13 bits = idx
      // Keys unique across segments (idx in low bits) -> equality = source.
      if (m == h0)      h0 = logbuf[(0 * QPB + tid) * CAPP + (p0++)];
      else if (m == h1) h1 = logbuf[(1 * QPB + tid) * CAPP + (p1++)];
      else if (m == h2) h2 = logbuf[(2 * QPB + tid) * CAPP + (p2++)];
      else              h3 = logbuf[(3 * QPB + tid) * CAPP + (p3++)];
    }
  }
}

extern "C" void kernel_launch(void* const* d_in, const int* in_sizes, int n_in,
                              void* d_out, int out_size, void* d_ws, size_t ws_size,
                              hipStream_t stream) {
  const float* x = (const float*)d_in[0];
  float* out = (float*)d_out;
  float* xxf = (float*)d_ws;  // 32768 floats = 128 KB scratch

  hipLaunchKernelGGL(knn_prep_kernel, dim3(NB * NP / 256), dim3(256), 0, stream,
                     x, out, xxf);
  hipLaunchKernelGGL(knn_main_kernel, dim3(NB * NP / QPB), dim3(TPB), 0, stream,
                     x, xxf, out + XOFF);
}